// Round 17
// baseline (49.530 us; speedup 1.0000x reference)
//
#include <hip/hip_runtime.h>
#include <math.h>

#define NT 100       // NUM_TOPICS
#define VOCAB 8192
#define TOPN 20
#define NWV 4        // waves per topk block
#define WCOLS 2048   // cols per wave
#define SCAP 256     // wave-private candidate capacity
#define HCOLS 4096   // cols per fused half-block

// ---- node 1: per-topic top-20 (VERBATIM R15/R16) + zero out/tflag ----
__global__ __launch_bounds__(256) void topk_kernel(
    const float* __restrict__ beta,
    int*   __restrict__ top_idx,   // [NT][TOPN]
    float* __restrict__ top_p,     // [NT][TOPN]
    float* __restrict__ rowstats,  // [NT][2] = {rowmax, full sumexp}
    int*   __restrict__ tflag,     // [NT] handshake counters
    float* __restrict__ out)
{
    const int k = blockIdx.x;
    const int t = threadIdx.x;
    const int wv = t >> 6;
    const int lane = t & 63;
    if (t == 0) tflag[k] = 0;               // block k zeroes its own topic's flag
    if (k == 0 && t == 0) *out = 0.f;

    __shared__ float cu[NWV * SCAP];
    __shared__ int   cid[NWV * SCAP];
    __shared__ float smaxs[NWV], ssums[NWV];
    __shared__ float pv[NWV * TOPN];
    __shared__ int   pid[NWV * TOPN];
    __shared__ float s_winv[TOPN];
    __shared__ int   s_wini[TOPN];
    __shared__ float s_ps, s_rowmax;

    const float* base = beta + (size_t)k * VOCAB + wv * WCOLS;
    float4 r[8];
    float mx = -INFINITY;
#pragma unroll
    for (int i = 0; i < 8; ++i) {
        r[i] = *reinterpret_cast<const float4*>(base + (size_t)(i * 64 + lane) * 4);
        mx = fmaxf(mx, fmaxf(fmaxf(r[i].x, r[i].y), fmaxf(r[i].z, r[i].w)));
    }
#pragma unroll
    for (int off = 32; off >= 1; off >>= 1) mx = fmaxf(mx, __shfl_xor(mx, off));
    const float smax = mx;

    float se = 0.f;
#pragma unroll
    for (int i = 0; i < 8; ++i) {
        se += expf(r[i].x - smax) + expf(r[i].y - smax)
            + expf(r[i].z - smax) + expf(r[i].w - smax);
    }
#pragma unroll
    for (int off = 32; off >= 1; off >>= 1) se += __shfl_xor(se, off);
    const float ssum = se;

    if (lane == 0) { smaxs[wv] = smax; ssums[wv] = ssum; }

    float T = smax - 1.5f;
    for (int g = 0; g < 16; ++g) {
        int c = 0;
#pragma unroll
        for (int i = 0; i < 8; ++i) {
            c += (r[i].x >= T) + (r[i].y >= T) + (r[i].z >= T) + (r[i].w >= T);
        }
#pragma unroll
        for (int off = 32; off >= 1; off >>= 1) c += __shfl_xor(c, off);
        if (c >= TOPN) break;
        T -= 0.4f;
    }

    int wbase = 0;
#pragma unroll
    for (int i = 0; i < 8; ++i) {
#pragma unroll
        for (int e = 0; e < 4; ++e) {
            const float v = (&r[i].x)[e];
            const bool pr = (v >= T);
            const unsigned long long mask = __ballot(pr);
            const int pre = __popcll(mask & ((1ull << lane) - 1ull));
            if (pr) {
                const int p = wbase + pre;
                if (p < SCAP) {
                    cu[wv * SCAP + p]  = v;
                    cid[wv * SCAP + p] = wv * WCOLS + (i * 64 + lane) * 4 + e;
                }
            }
            wbase += __popcll(mask);
        }
    }
    const int n = min(wbase, SCAP);

    for (int it = 0; it < TOPN; ++it) {
        float bv = -INFINITY; int bp = -1;
        for (int p = lane; p < n; p += 64) {
            const float v = cu[wv * SCAP + p];
            if (v > bv) { bv = v; bp = p; }
        }
#pragma unroll
        for (int off = 32; off >= 1; off >>= 1) {
            const float ov = __shfl_down(bv, off);
            const int   op = __shfl_down(bp, off);
            if (ov > bv) { bv = ov; bp = op; }
        }
        bp = __shfl(bp, 0);
        bv = __shfl(bv, 0);
        if (lane == 0) {
            pv[wv * TOPN + it]  = bv;
            pid[wv * TOPN + it] = (bp >= 0) ? cid[wv * SCAP + bp] : 0;
        }
        if (bp >= 0) cu[wv * SCAP + bp] = -INFINITY;
    }
    __syncthreads();

    if (wv == 0) {
        for (int it = 0; it < TOPN; ++it) {
            float bv = -INFINITY; int bp = -1;
            for (int p = lane; p < NWV * TOPN; p += 64) {
                const float v = pv[p];
                if (v > bv) { bv = v; bp = p; }
            }
#pragma unroll
            for (int off = 32; off >= 1; off >>= 1) {
                const float ov = __shfl_down(bv, off);
                const int   op = __shfl_down(bp, off);
                if (ov > bv) { bv = ov; bp = op; }
            }
            bp = __shfl(bp, 0);
            bv = __shfl(bv, 0);
            if (lane == 0) { s_winv[it] = bv; s_wini[it] = pid[bp]; }
            pv[bp] = -INFINITY;
        }
        if (lane == 0) {
            const float rowmax = s_winv[0];
            float ps = 0.f;
#pragma unroll
            for (int j = 0; j < TOPN; ++j) ps += expf(s_winv[j] - rowmax);
            float rs = 0.f;
#pragma unroll
            for (int s = 0; s < NWV; ++s) rs += ssums[s] * expf(smaxs[s] - rowmax);
            s_rowmax = rowmax;
            s_ps = ps;
            rowstats[2 * k + 0] = rowmax;
            rowstats[2 * k + 1] = rs;
        }
    }
    __syncthreads();
    if (t < TOPN) {
        top_idx[k * TOPN + t] = s_wini[t];
        top_p[k * TOPN + t]   = expf(s_winv[t] - s_rowmax) / s_ps;
    }
}

// ---- node 2: fused gather + loss, topic x half (200 x 1024), pairwise handshake ----
__global__ __launch_bounds__(1024) void fused_kernel(
    const float* __restrict__ beta,
    const float* __restrict__ W,
    const int*   __restrict__ top_idx,
    const float* __restrict__ top_p,
    const float* __restrict__ rowstats,
    const int*   __restrict__ epoch,
    float* __restrict__ part6,   // [NT*2][6]
    int*   __restrict__ tflag,   // [NT]
    float* __restrict__ out)
{
    const int b = blockIdx.x;
    const int k = b >> 1;
    const int h = b & 1;
    const int t = threadIdx.x;
    const int lo = h * HCOLS;

    __shared__ int   cnt[HCOLS];             // 16 KB half-row histogram
    __shared__ int   sIdx[TOPN];
    __shared__ float sP[TOPN];
    __shared__ float sA[16], sB[16], sC[16], sD[16], sE[16], sF[16];
    __shared__ int   s_old;

    if (t < TOPN) { sIdx[t] = top_idx[k * TOPN + t]; sP[t] = top_p[k * TOPN + t]; }
#pragma unroll
    for (int i = 0; i < HCOLS / 1024; ++i) cnt[i * 1024 + t] = 0;
    __syncthreads();

    // half-local histogram over all topics' top-20, minus own topic
#pragma unroll 2
    for (int e = t; e < NT * TOPN; e += 1024) {
        const int v = top_idx[e] - lo;
        if ((unsigned)v < (unsigned)HCOLS) atomicAdd(&cnt[v], 1);
    }
    if (t < TOPN) {
        const int v = sIdx[t] - lo;
        if ((unsigned)v < (unsigned)HCOLS) atomicSub(&cnt[v], 1);
    }

    int   idx_r[TOPN];
    float p_r[TOPN];
#pragma unroll
    for (int j = 0; j < TOPN; ++j) { idx_r[j] = sIdx[j]; p_r[j] = sP[j]; }

    const float rmax = rowstats[2 * k + 0];
    const float rinv = 1.0f / rowstats[2 * k + 1];

    __syncthreads();                         // cnt final

    const int col = lo + t * 4;              // 1024 thr x float4 = 4096 cols
    float4 m = make_float4(0.f, 0.f, 0.f, 0.f);
#pragma unroll
    for (int j = 0; j < TOPN; ++j) {
        const float4 w = *reinterpret_cast<const float4*>(W + (size_t)idx_r[j] * VOCAB + col);
        const float pj = p_r[j];
        m.x += pj * w.x; m.y += pj * w.y; m.z += pj * w.z; m.w += pj * w.w;
    }
    float mn  = fminf(fminf(m.x, m.y), fminf(m.z, m.w));
    float mxv = fmaxf(fmaxf(m.x, m.y), fmaxf(m.z, m.w));

    const float4 bv = *reinterpret_cast<const float4*>(beta + (size_t)k * VOCAB + col);
    float4 w4;
    w4.x = expf(bv.x - rmax) * rinv;  w4.x = 100.f * w4.x * w4.x;
    w4.y = expf(bv.y - rmax) * rinv;  w4.y = 100.f * w4.y * w4.y;
    w4.z = expf(bv.z - rmax) * rinv;  w4.z = 100.f * w4.z * w4.z;
    w4.w = expf(bv.w - rmax) * rinv;  w4.w = 100.f * w4.w * w4.w;

    float Apos = 0.f, Bpos = 0.f, Aneg = 0.f, Bneg = 0.f;
    {
        const int lc = t * 4;
        if (cnt[lc + 0] > 0) { Apos += w4.x; Bpos += w4.x * m.x; } else { Aneg += w4.x; Bneg += w4.x * m.x; }
        if (cnt[lc + 1] > 0) { Apos += w4.y; Bpos += w4.y * m.y; } else { Aneg += w4.y; Bneg += w4.y * m.y; }
        if (cnt[lc + 2] > 0) { Apos += w4.z; Bpos += w4.z * m.z; } else { Aneg += w4.z; Bneg += w4.z * m.z; }
        if (cnt[lc + 3] > 0) { Apos += w4.w; Bpos += w4.w * m.w; } else { Aneg += w4.w; Bneg += w4.w * m.w; }
    }

#pragma unroll
    for (int off = 32; off >= 1; off >>= 1) {
        mn   = fminf(mn,  __shfl_down(mn,  off));
        mxv  = fmaxf(mxv, __shfl_down(mxv, off));
        Apos += __shfl_down(Apos, off);
        Bpos += __shfl_down(Bpos, off);
        Aneg += __shfl_down(Aneg, off);
        Bneg += __shfl_down(Bneg, off);
    }
    if ((t & 63) == 0) {
        const int w = t >> 6;
        sA[w] = mn; sB[w] = mxv; sC[w] = Apos; sD[w] = Bpos; sE[w] = Aneg; sF[w] = Bneg;
    }
    __syncthreads();

    if (t == 0) {
        float a = sA[0], bb = sB[0], Ap = 0.f, Bp = 0.f, An = 0.f, Bn = 0.f;
#pragma unroll
        for (int w = 0; w < 16; ++w) {
            a  = fminf(a, sA[w]);
            bb = fmaxf(bb, sB[w]);
            Ap += sC[w]; Bp += sD[w]; An += sE[w]; Bn += sF[w];
        }
        float* p6 = part6 + (size_t)b * 6;
        p6[0] = a; p6[1] = bb; p6[2] = Ap; p6[3] = Bp; p6[4] = An; p6[5] = Bn;
        __threadfence();                     // release partials (device scope)
        s_old = atomicAdd(&tflag[k], 1);
        if (s_old == 1) {                    // second arriver finalizes
            __threadfence();                 // acquire other half's partials
            const float* q0 = part6 + (size_t)(2 * k + 0) * 6;
            const float* q1 = part6 + (size_t)(2 * k + 1) * 6;
            const float gmn = fminf(q0[0], q1[0]);
            const float gmx = fmaxf(q0[1], q1[1]);
            const float A_p = q0[2] + q1[2];
            const float B_p = q0[3] + q1[3];
            const float A_n = q0[4] + q1[4];
            const float B_n = q0[5] + q1[5];
            const float inv = 1.0f / (gmx - gmn);
            const float pos = A_p - inv * (B_p - gmn * A_p);
            const float neg = A_n - inv * (B_n - gmn * A_n);
            const int e = *epoch;
            const float la = (e < 100) ? (float)e : 100.0f;   // lambda_a_delta = 1
            atomicAdd(out, la * (pos * 0.7f + neg * 0.3f) * 2.0f);
        }
    }
}

extern "C" void kernel_launch(void* const* d_in, const int* in_sizes, int n_in,
                              void* d_out, int out_size, void* d_ws, size_t ws_size,
                              hipStream_t stream)
{
    (void)in_sizes; (void)n_in; (void)out_size; (void)ws_size;
    const float* beta  = (const float*)d_in[0];
    const float* W     = (const float*)d_in[1];
    const int*   epoch = (const int*)d_in[2];
    float* out = (float*)d_out;

    char* ws = (char*)d_ws;
    int*   top_idx  = (int*)ws;    ws += NT * TOPN * sizeof(int);
    float* top_p    = (float*)ws;  ws += NT * TOPN * sizeof(float);
    float* rowstats = (float*)ws;  ws += NT * 2 * sizeof(float);
    ws = (char*)(((size_t)ws + 255) & ~(size_t)255);
    float* part6    = (float*)ws;  ws += NT * 2 * 6 * sizeof(float);
    ws = (char*)(((size_t)ws + 255) & ~(size_t)255);
    int*   tflag    = (int*)ws;    ws += NT * 64;   // one cacheline per topic

    topk_kernel<<<NT, 256, 0, stream>>>(beta, top_idx, top_p, rowstats, tflag, out);
    fused_kernel<<<NT * 2, 1024, 0, stream>>>(beta, W, top_idx, top_p, rowstats,
                                              epoch, part6, tflag, out);
}

// Round 18
// 47.064 us; speedup vs baseline: 1.0524x; 1.0524x over previous
//
#include <hip/hip_runtime.h>
#include <math.h>

#define NT 100       // NUM_TOPICS
#define VOCAB 8192
#define TOPN 20
#define NWV 4        // waves per topk block
#define WCOLS 2048   // cols per wave
#define SCAP 256     // wave-private candidate capacity

// ---- node 1: per-topic top-20, all phases wave-local (R15-proven) + zero out ----
__global__ __launch_bounds__(256) void topk_kernel(
    const float* __restrict__ beta,
    int*   __restrict__ top_idx,   // [NT][TOPN]
    float* __restrict__ top_p,     // [NT][TOPN]
    float* __restrict__ rowstats,  // [NT][2] = {rowmax, full sumexp}
    float* __restrict__ out)
{
    const int k = blockIdx.x;
    const int t = threadIdx.x;
    const int wv = t >> 6;          // wave 0..3
    const int lane = t & 63;
    if (k == 0 && t == 0) *out = 0.f;

    __shared__ float cu[NWV * SCAP];        // 4 KB wave-private candidates
    __shared__ int   cid[NWV * SCAP];       // 4 KB
    __shared__ float smaxs[NWV], ssums[NWV];
    __shared__ float pv[NWV * TOPN];        // 80 pre-candidates
    __shared__ int   pid[NWV * TOPN];
    __shared__ float s_winv[TOPN];
    __shared__ int   s_wini[TOPN];
    __shared__ float s_ps, s_rowmax;

    const float* base = beta + (size_t)k * VOCAB + wv * WCOLS;
    float4 r[8];
    float mx = -INFINITY;
#pragma unroll
    for (int i = 0; i < 8; ++i) {
        r[i] = *reinterpret_cast<const float4*>(base + (size_t)(i * 64 + lane) * 4);
        mx = fmaxf(mx, fmaxf(fmaxf(r[i].x, r[i].y), fmaxf(r[i].z, r[i].w)));
    }
#pragma unroll
    for (int off = 32; off >= 1; off >>= 1) mx = fmaxf(mx, __shfl_xor(mx, off));
    const float smax = mx;

    float se = 0.f;
#pragma unroll
    for (int i = 0; i < 8; ++i) {
        se += expf(r[i].x - smax) + expf(r[i].y - smax)
            + expf(r[i].z - smax) + expf(r[i].w - smax);
    }
#pragma unroll
    for (int off = 32; off >= 1; off >>= 1) se += __shfl_xor(se, off);
    const float ssum = se;

    if (lane == 0) { smaxs[wv] = smax; ssums[wv] = ssum; }

    float T = smax - 1.5f;
    for (int g = 0; g < 16; ++g) {
        int c = 0;
#pragma unroll
        for (int i = 0; i < 8; ++i) {
            c += (r[i].x >= T) + (r[i].y >= T) + (r[i].z >= T) + (r[i].w >= T);
        }
#pragma unroll
        for (int off = 32; off >= 1; off >>= 1) c += __shfl_xor(c, off);
        if (c >= TOPN) break;               // wave-uniform decision
        T -= 0.4f;
    }

    int wbase = 0;
#pragma unroll
    for (int i = 0; i < 8; ++i) {
#pragma unroll
        for (int e = 0; e < 4; ++e) {
            const float v = (&r[i].x)[e];
            const bool pr = (v >= T);
            const unsigned long long mask = __ballot(pr);
            const int pre = __popcll(mask & ((1ull << lane) - 1ull));
            if (pr) {
                const int p = wbase + pre;
                if (p < SCAP) {
                    cu[wv * SCAP + p]  = v;
                    cid[wv * SCAP + p] = wv * WCOLS + (i * 64 + lane) * 4 + e;
                }
            }
            wbase += __popcll(mask);        // wave-uniform
        }
    }
    const int n = min(wbase, SCAP);

    for (int it = 0; it < TOPN; ++it) {
        float bv = -INFINITY; int bp = -1;
        for (int p = lane; p < n; p += 64) {
            const float v = cu[wv * SCAP + p];
            if (v > bv) { bv = v; bp = p; }
        }
#pragma unroll
        for (int off = 32; off >= 1; off >>= 1) {
            const float ov = __shfl_down(bv, off);
            const int   op = __shfl_down(bp, off);
            if (ov > bv) { bv = ov; bp = op; }
        }
        bp = __shfl(bp, 0);
        bv = __shfl(bv, 0);
        if (lane == 0) {
            pv[wv * TOPN + it]  = bv;
            pid[wv * TOPN + it] = (bp >= 0) ? cid[wv * SCAP + bp] : 0;
        }
        if (bp >= 0) cu[wv * SCAP + bp] = -INFINITY;
    }
    __syncthreads();

    if (wv == 0) {
        for (int it = 0; it < TOPN; ++it) {
            float bv = -INFINITY; int bp = -1;
            for (int p = lane; p < NWV * TOPN; p += 64) {
                const float v = pv[p];
                if (v > bv) { bv = v; bp = p; }
            }
#pragma unroll
            for (int off = 32; off >= 1; off >>= 1) {
                const float ov = __shfl_down(bv, off);
                const int   op = __shfl_down(bp, off);
                if (ov > bv) { bv = ov; bp = op; }
            }
            bp = __shfl(bp, 0);
            bv = __shfl(bv, 0);
            if (lane == 0) { s_winv[it] = bv; s_wini[it] = pid[bp]; }
            pv[bp] = -INFINITY;
        }
        if (lane == 0) {
            const float rowmax = s_winv[0];
            float ps = 0.f;
#pragma unroll
            for (int j = 0; j < TOPN; ++j) ps += expf(s_winv[j] - rowmax);
            float rs = 0.f;
#pragma unroll
            for (int s = 0; s < NWV; ++s) rs += ssums[s] * expf(smaxs[s] - rowmax);
            s_rowmax = rowmax;
            s_ps = ps;
            rowstats[2 * k + 0] = rowmax;
            rowstats[2 * k + 1] = rs;
        }
    }
    __syncthreads();
    if (t < TOPN) {
        top_idx[k * TOPN + t] = s_wini[t];
        top_p[k * TOPN + t]   = expf(s_winv[t] - s_rowmax) / s_ps;
    }
}

// ---- node 2: fused gather + loss + per-topic finalize (100 x 1024) ----
__global__ __launch_bounds__(1024) void fused_kernel(
    const float* __restrict__ beta,
    const float* __restrict__ W,
    const int*   __restrict__ top_idx,
    const float* __restrict__ top_p,
    const float* __restrict__ rowstats,
    const int*   __restrict__ epoch,
    float* __restrict__ out)
{
    const int k = blockIdx.x;
    const int t = threadIdx.x;

    __shared__ int   cnt[VOCAB];             // 32 KB full-row histogram
    __shared__ int   sIdx[TOPN];
    __shared__ float sP[TOPN];
    __shared__ float sA[16], sB[16], sC[16], sD[16], sE[16], sF[16];

    if (t < TOPN) { sIdx[t] = top_idx[k * TOPN + t]; sP[t] = top_p[k * TOPN + t]; }
#pragma unroll
    for (int i = 0; i < VOCAB / 1024; ++i) cnt[i * 1024 + t] = 0;
    __syncthreads();

    // full-row histogram over all topics' top-20 (2000 entries), minus own topic
#pragma unroll 2
    for (int e = t; e < NT * TOPN; e += 1024) atomicAdd(&cnt[top_idx[e]], 1);
    if (t < TOPN) atomicSub(&cnt[sIdx[t]], 1);

    int   idx_r[TOPN];
    float p_r[TOPN];
#pragma unroll
    for (int j = 0; j < TOPN; ++j) { idx_r[j] = sIdx[j]; p_r[j] = sP[j]; }

    const float rmax = rowstats[2 * k + 0];
    const float rinv = 1.0f / rowstats[2 * k + 1];

    __syncthreads();                         // cnt final

    float mn = INFINITY, mxv = -INFINITY;
    float Apos = 0.f, Bpos = 0.f, Aneg = 0.f, Bneg = 0.f;

#pragma unroll
    for (int seg = 0; seg < 2; ++seg) {      // 2 segments x 1024 thr x float4
        const int col = seg * 4096 + t * 4;

        float4 m = make_float4(0.f, 0.f, 0.f, 0.f);
#pragma unroll
        for (int j = 0; j < TOPN; ++j) {
            const float4 w = *reinterpret_cast<const float4*>(W + (size_t)idx_r[j] * VOCAB + col);
            const float pj = p_r[j];
            m.x += pj * w.x; m.y += pj * w.y; m.z += pj * w.z; m.w += pj * w.w;
        }
        mn  = fminf(mn,  fminf(fminf(m.x, m.y), fminf(m.z, m.w)));
        mxv = fmaxf(mxv, fmaxf(fmaxf(m.x, m.y), fmaxf(m.z, m.w)));

        const float4 bv = *reinterpret_cast<const float4*>(beta + (size_t)k * VOCAB + col);
        float4 w4;
        w4.x = expf(bv.x - rmax) * rinv;  w4.x = 100.f * w4.x * w4.x;
        w4.y = expf(bv.y - rmax) * rinv;  w4.y = 100.f * w4.y * w4.y;
        w4.z = expf(bv.z - rmax) * rinv;  w4.z = 100.f * w4.z * w4.z;
        w4.w = expf(bv.w - rmax) * rinv;  w4.w = 100.f * w4.w * w4.w;

        const int4 c4 = *reinterpret_cast<const int4*>(cnt + col);
        if (c4.x > 0) { Apos += w4.x; Bpos += w4.x * m.x; } else { Aneg += w4.x; Bneg += w4.x * m.x; }
        if (c4.y > 0) { Apos += w4.y; Bpos += w4.y * m.y; } else { Aneg += w4.y; Bneg += w4.y * m.y; }
        if (c4.z > 0) { Apos += w4.z; Bpos += w4.z * m.z; } else { Aneg += w4.z; Bneg += w4.z * m.z; }
        if (c4.w > 0) { Apos += w4.w; Bpos += w4.w * m.w; } else { Aneg += w4.w; Bneg += w4.w * m.w; }
    }

#pragma unroll
    for (int off = 32; off >= 1; off >>= 1) {
        mn   = fminf(mn,  __shfl_down(mn,  off));
        mxv  = fmaxf(mxv, __shfl_down(mxv, off));
        Apos += __shfl_down(Apos, off);
        Bpos += __shfl_down(Bpos, off);
        Aneg += __shfl_down(Aneg, off);
        Bneg += __shfl_down(Bneg, off);
    }
    if ((t & 63) == 0) {
        const int w = t >> 6;
        sA[w] = mn; sB[w] = mxv; sC[w] = Apos; sD[w] = Bpos; sE[w] = Aneg; sF[w] = Bneg;
    }
    __syncthreads();
    if (t == 0) {
        float a = sA[0], b = sB[0], Ap = 0.f, Bp = 0.f, An = 0.f, Bn = 0.f;
#pragma unroll
        for (int w = 0; w < 16; ++w) {
            a  = fminf(a, sA[w]);
            b  = fmaxf(b, sB[w]);
            Ap += sC[w]; Bp += sD[w]; An += sE[w]; Bn += sF[w];
        }
        const float inv = 1.0f / (b - a);
        const float pos = Ap - inv * (Bp - a * Ap);   // sum w*(1-(M-mn)*inv)
        const float neg = An - inv * (Bn - a * An);
        const int e = *epoch;
        const float la = (e < 100) ? (float)e : 100.0f;   // lambda_a_delta = 1
        atomicAdd(out, la * (pos * 0.7f + neg * 0.3f) * 2.0f);
    }
}

extern "C" void kernel_launch(void* const* d_in, const int* in_sizes, int n_in,
                              void* d_out, int out_size, void* d_ws, size_t ws_size,
                              hipStream_t stream)
{
    (void)in_sizes; (void)n_in; (void)out_size; (void)ws_size;
    const float* beta  = (const float*)d_in[0];
    const float* W     = (const float*)d_in[1];
    const int*   epoch = (const int*)d_in[2];
    float* out = (float*)d_out;

    char* ws = (char*)d_ws;
    int*   top_idx  = (int*)ws;    ws += NT * TOPN * sizeof(int);
    float* top_p    = (float*)ws;  ws += NT * TOPN * sizeof(float);
    float* rowstats = (float*)ws;  ws += NT * 2 * sizeof(float);

    topk_kernel<<<NT, 256, 0, stream>>>(beta, top_idx, top_p, rowstats, out);
    fused_kernel<<<NT, 1024, 0, stream>>>(beta, W, top_idx, top_p, rowstats, epoch, out);
}